// Round 9
// baseline (402.871 us; speedup 1.0000x reference)
//
#include <hip/hip_runtime.h>
#include <math.h>

// GatedSpikingReservoirStep — fp16-single MFMA fused kernel + fp64 fixup.
// Round 15: r13/r14 (depth-3 counted-vmcnt, 96KB LDS) killed the container
// twice — cannot distinguish infra from kernel-wedge, and r2-r4 proved the
// counted-vmcnt machinery is perf-neutral anyway. This round tests the BYTE
// REDUCTION theory alone on the maximally-proven schedule:
//   - 256x128 tile (staged = nblk*(BM+BN)*K*2B = 768MB, was 1.57GB r6) —
//     the only lever that correlated with time across r0-r6
//     (time ~= staged_bytes / 4.5-6 TB/s at this shape).
//   - 512 thr / 8 waves (4m x 2n), wave owns 64x64: acc[4][4]+u[4][4]=128.
//   - r1's exact K-step schedule (ran in r1+r6): __syncthreads; 3x gld16;
//     __syncthreads; plain C++ LDS reads; 16 MFMA. Single 24KB LDS buffer.
//   - bijective XCD swizzle (4m x 8n block chunk per XCD) vs the measured
//     8x A-panel HBM duplication (FETCH 212MB ~= S16 x8 + X x8).
// r0-verified chunk-XOR LDS swizzle; identical fp32 epilogue -> absmax same.

#define IDIM 512
#define DDIM 2048
#define MAXD 2560
#define BDIM 4096
#define LIST_CAP 262144
#define BAND 4e-3f

typedef __attribute__((ext_vector_type(4))) float f32x4;
typedef __attribute__((ext_vector_type(8))) _Float16 f16x8;

__device__ __forceinline__ void gld16(const unsigned short* g, unsigned short* l) {
    __builtin_amdgcn_global_load_lds((const __attribute__((address_space(1))) void*)g,
                                     (__attribute__((address_space(3))) void*)l,
                                     16, 0, 0);
}
__device__ __forceinline__ float sigf(float x) { return 1.0f / (1.0f + __expf(-x)); }

// ---------------------------------------------------------------------------
// convert: fp32 -> fp16 for X, S=state[:, :2048], Wc=[Win;Wgate], Wr;
// zero out-pad; zero fixup counter. 20480 blocks x 256 (float4 units).
// ---------------------------------------------------------------------------
__global__ __launch_bounds__(256) void convert_kernel(
    const float* __restrict__ x, const float* __restrict__ state,
    const float* __restrict__ win, const float* __restrict__ wgate,
    const float* __restrict__ wres,
    unsigned short* __restrict__ X16, unsigned short* __restrict__ S16,
    unsigned short* __restrict__ Wc16, unsigned short* __restrict__ Wr16,
    float* __restrict__ out, unsigned* __restrict__ cnt)
{
    int idx = blockIdx.x * 256 + threadIdx.x;
    if (idx == 0) *cnt = 0u;
    float4 v;
    unsigned short* p;
    long off;
    if (idx < 524288) {
        v = ((const float4*)x)[idx];
        p = X16; off = (long)idx * 4;
    } else if (idx < 2621440) {
        int i = idx - 524288;
        int row = i >> 9, c4 = i & 511;
        v = *(const float4*)(state + (long)row * MAXD + c4 * 4);
        p = S16; off = (long)i * 4;
    } else if (idx < 3670016) {
        int i = idx - 2621440;
        v = (i < 262144) ? ((const float4*)win)[i] : ((const float4*)wgate)[i - 262144];
        p = Wc16; off = (long)i * 4;
    } else if (idx < 4718592) {
        int i = idx - 3670016;
        v = ((const float4*)wres)[i];
        p = Wr16; off = (long)i * 4;
    } else {
        int i = idx - 4718592;
        int row = i >> 7, c4 = i & 127;
        *(float4*)(out + (long)row * MAXD + DDIM + c4 * 4) = make_float4(0.f, 0.f, 0.f, 0.f);
        return;
    }
    _Float16 h0 = (_Float16)v.x, h1 = (_Float16)v.y;
    _Float16 h2 = (_Float16)v.z, h3 = (_Float16)v.w;
    ushort4 hv;
    hv.x = *(unsigned short*)&h0; hv.y = *(unsigned short*)&h1;
    hv.z = *(unsigned short*)&h2; hv.w = *(unsigned short*)&h3;
    *(ushort4*)(p + off) = hv;
}

// ---------------------------------------------------------------------------
// fused_step: 5 GEMM phases (virtual K=4096) + gating epilogue, 256x128 tile.
// 8 waves (4m x 2n), each owns 64x64: acc[4][4] + u[4][4]. BK=32, single
// 24KB LDS buffer (A 256x32 hw @ [0,8192), B 128x32 hw @ [8192,12288)).
// Per K-step: sync; wave stages its 32 A-rows (2 gld16) + 16 B-rows (1);
// sync; plain LDS fragment reads; 16 MFMA. r1-proven structure.
// XCD swizzle: nb = (bid&7)*32 + bid>>3; XCD owns a 4m x 8n block chunk.
// ---------------------------------------------------------------------------
__global__ __launch_bounds__(512, 1) void fused_step(
    const unsigned short* __restrict__ X16, const unsigned short* __restrict__ S16,
    const unsigned short* __restrict__ Wc16, const unsigned short* __restrict__ Wr16,
    const float* __restrict__ state, float* __restrict__ out,
    unsigned* __restrict__ cnt, unsigned* __restrict__ list)
{
    __shared__ alignas(16) unsigned short ldsm[12288];   // 24 KiB: A 16K + B 8K
    const int t = threadIdx.x;
    const int wave = t >> 6, lane = t & 63;
    const int wr = wave >> 1, wc = wave & 1;             // wr 0..3 (m), wc 0..1 (n)
    const int quad = lane >> 4, l16 = lane & 15;

    // bijective XCD swizzle (256 blocks, 8 XCDs): XCD k owns nb in [32k,32k+32)
    const int bid = blockIdx.x;
    const int nb  = (bid & 7) * 32 + (bid >> 3);
    const int xcd = nb >> 5, lid = nb & 31;
    const int m0 = ((xcd >> 1) * 4 + (lid >> 3)) * 256;  // 16 m-tiles
    const int n0 = ((xcd & 1) * 8 + (lid & 7)) * 128;    // 16 n-tiles

    const int rowoff = lane >> 2;                         // 0..15
    const int kg = ((lane & 3) ^ ((lane >> 3) & 3)) * 8;  // write-side chunk swizzle (hw)
    const int krh = (quad ^ ((l16 >> 1) & 3)) * 8;        // read-side chunk (hw)

    f32x4 acc[4][4];
    f32x4 u[4][4];    // sum -> 0.2*tanh(i*sum) -> + 0.8*f*prev  (2 live sets)

    #pragma unroll
    for (int mi = 0; mi < 4; mi++)
        #pragma unroll
        for (int ni = 0; ni < 4; ni++)
            acc[mi][ni] = (f32x4)0.0f;

    auto phase = [&](const unsigned short* Ag, long ldA,
                     const unsigned short* Bg, long ldB, int klen) {
        const unsigned short* a0 = Ag + (long)(wave * 32 + rowoff) * ldA + kg;
        const unsigned short* a1 = a0 + (long)16 * ldA;
        const unsigned short* b0 = Bg + (long)(wave * 16 + rowoff) * ldB + kg;
        unsigned short* dA = ldsm + wave * 1024;          // 32 rows x 64B
        unsigned short* dB = ldsm + 8192 + wave * 512;    // 16 rows x 64B
        for (int k0 = 0; k0 < klen; k0 += 32) {
            __syncthreads();
            gld16(a0 + k0, dA);
            gld16(a1 + k0, dA + 512);
            gld16(b0 + k0, dB);
            __syncthreads();
            f16x8 af[4], bf[4];
            #pragma unroll
            for (int mi = 0; mi < 4; mi++)
                af[mi] = *(const f16x8*)&ldsm[(wr * 64 + mi * 16 + l16) * 32 + krh];
            #pragma unroll
            for (int ni = 0; ni < 4; ni++)
                bf[ni] = *(const f16x8*)&ldsm[8192 + (wc * 64 + ni * 16 + l16) * 32 + krh];
            #pragma unroll
            for (int mi = 0; mi < 4; mi++)
                #pragma unroll
                for (int ni = 0; ni < 4; ni++)
                    acc[mi][ni] = __builtin_amdgcn_mfma_f32_16x16x32_f16(af[mi], bf[ni], acc[mi][ni], 0, 0, 0);
        }
    };

    // Phase 0: acc = prev @ Wres^T          (K = 2048)
    phase(S16 + (long)m0 * DDIM, DDIM, Wr16 + (long)n0 * DDIM, DDIM, DDIM);
    // Phase 1: acc += X @ Win^T  -> u = ip + rp   (K = 512)
    phase(X16 + (long)m0 * IDIM, IDIM, Wc16 + (long)n0 * IDIM, IDIM, IDIM);
    #pragma unroll
    for (int mi = 0; mi < 4; mi++)
        #pragma unroll
        for (int ni = 0; ni < 4; ni++) { u[mi][ni] = acc[mi][ni]; acc[mi][ni] = (f32x4)0.0f; }

    // Phase 2: acc = X @ Wg_i^T  -> u = 0.2*tanh(sig(acc)*u)
    phase(X16 + (long)m0 * IDIM, IDIM, Wc16 + (long)(DDIM + n0) * IDIM, IDIM, IDIM);
    #pragma unroll
    for (int mi = 0; mi < 4; mi++)
        #pragma unroll
        for (int ni = 0; ni < 4; ni++) {
            #pragma unroll
            for (int r = 0; r < 4; r++)
                u[mi][ni][r] = 0.2f * tanhf(sigf(acc[mi][ni][r]) * u[mi][ni][r]);
            acc[mi][ni] = (f32x4)0.0f;
        }

    // Phase 3: acc = X @ Wg_f^T  -> u += 0.8*sig(acc)*prev
    phase(X16 + (long)m0 * IDIM, IDIM, Wc16 + (long)(2 * DDIM + n0) * IDIM, IDIM, IDIM);
    #pragma unroll
    for (int mi = 0; mi < 4; mi++)
        #pragma unroll
        for (int ni = 0; ni < 4; ni++) {
            #pragma unroll
            for (int r = 0; r < 4; r++) {
                int row = m0 + wr * 64 + mi * 16 + quad * 4 + r;
                int col = n0 + wc * 64 + ni * 16 + l16;
                float prev = state[(long)row * MAXD + col];
                u[mi][ni][r] += 0.8f * sigf(acc[mi][ni][r]) * prev;
            }
            acc[mi][ni] = (f32x4)0.0f;
        }

    // Phase 4: acc = X @ Wg_o^T  -> ns = sig(acc)*u -> spike -> write
    phase(X16 + (long)m0 * IDIM, IDIM, Wc16 + (long)(3 * DDIM + n0) * IDIM, IDIM, IDIM);
    #pragma unroll
    for (int mi = 0; mi < 4; mi++)
        #pragma unroll
        for (int ni = 0; ni < 4; ni++) {
            #pragma unroll
            for (int r = 0; r < 4; r++) {
                int row = m0 + wr * 64 + mi * 16 + quad * 4 + r;
                int col = n0 + wc * 64 + ni * 16 + l16;
                float go = sigf(acc[mi][ni][r]);
                float ns = go * u[mi][ni][r];
                float ov = (ns > 0.5f) ? ns - 0.5f : ns;
                out[(long)row * MAXD + col] = ov;
                if (fabsf(ns - 0.5f) < BAND) {
                    unsigned pos = atomicAdd(cnt, 1u);
                    if (pos < LIST_CAP) list[pos] = (unsigned)(row * DDIM + col);
                }
            }
        }
}

// ---------------------------------------------------------------------------
// fixup: recompute flagged elements exactly in fp64, float4-vectorized loads.
// ---------------------------------------------------------------------------
__global__ __launch_bounds__(256) void fixup_kernel(
    const float* __restrict__ x, const float* __restrict__ state,
    const float* __restrict__ win, const float* __restrict__ wres,
    const float* __restrict__ wgate,
    const unsigned* __restrict__ cnt, const unsigned* __restrict__ list,
    float* __restrict__ out)
{
    const int gwave = (blockIdx.x * 256 + threadIdx.x) >> 6;
    const int lane = threadIdx.x & 63;
    const int nwaves = gridDim.x * 4;
    unsigned n = *cnt;
    if (n > LIST_CAP) n = LIST_CAP;
    for (unsigned e = gwave; e < n; e += nwaves) {
        unsigned rc = list[e];
        int row = rc >> 11, col = rc & 2047;
        double ip = 0.0, gi = 0.0, gf = 0.0, go = 0.0, rp = 0.0;
        const float* xr  = x + (long)row * IDIM;
        const float* wi  = win + (long)col * IDIM;
        const float* wgi = wgate + (long)col * IDIM;
        const float* wgf = wgate + (long)(DDIM + col) * IDIM;
        const float* wgo = wgate + (long)(2 * DDIM + col) * IDIM;
        #pragma unroll
        for (int k = lane * 4; k < IDIM; k += 256) {
            float4 xv = *(const float4*)(xr + k);
            float4 a = *(const float4*)(wi + k);
            float4 b = *(const float4*)(wgi + k);
            float4 c = *(const float4*)(wgf + k);
            float4 d = *(const float4*)(wgo + k);
            ip += (double)xv.x * a.x + (double)xv.y * a.y + (double)xv.z * a.z + (double)xv.w * a.w;
            gi += (double)xv.x * b.x + (double)xv.y * b.y + (double)xv.z * b.z + (double)xv.w * b.w;
            gf += (double)xv.x * c.x + (double)xv.y * c.y + (double)xv.z * c.z + (double)xv.w * c.w;
            go += (double)xv.x * d.x + (double)xv.y * d.y + (double)xv.z * d.z + (double)xv.w * d.w;
        }
        const float* sr = state + (long)row * MAXD;
        const float* wr_ = wres + (long)col * DDIM;
        #pragma unroll 2
        for (int k = lane * 4; k < DDIM; k += 256) {
            float4 sv = *(const float4*)(sr + k);
            float4 wv = *(const float4*)(wr_ + k);
            rp += (double)sv.x * wv.x + (double)sv.y * wv.y + (double)sv.z * wv.z + (double)sv.w * wv.w;
        }
        #pragma unroll
        for (int o = 32; o > 0; o >>= 1) {
            ip += __shfl_down(ip, o);
            gi += __shfl_down(gi, o);
            gf += __shfl_down(gf, o);
            go += __shfl_down(go, o);
            rp += __shfl_down(rp, o);
        }
        if (lane == 0) {
            double si = 1.0 / (1.0 + exp(-gi));
            double sf = 1.0 / (1.0 + exp(-gf));
            double so = 1.0 / (1.0 + exp(-go));
            double prev = (double)state[(long)row * MAXD + col];
            double ns = so * (0.8 * sf * prev + 0.2 * tanh(si * (ip + rp)));
            if (ns > 0.5) ns -= 0.5;
            out[(long)row * MAXD + col] = (float)ns;
        }
    }
}

extern "C" void kernel_launch(void* const* d_in, const int* in_sizes, int n_in,
                              void* d_out, int out_size, void* d_ws, size_t ws_size,
                              hipStream_t stream) {
    const float* x     = (const float*)d_in[0];   // (4096, 512)
    const float* state = (const float*)d_in[1];   // (4096, 2560)
    const float* win   = (const float*)d_in[2];   // (2048, 512)
    const float* wres  = (const float*)d_in[3];   // (2048, 2048)
    const float* wgate = (const float*)d_in[4];   // (6144, 512)
    float* out = (float*)d_out;

    char* ws = (char*)d_ws;
    unsigned short* X16  = (unsigned short*)(ws);                   //  0.. 4 MiB
    unsigned short* S16  = (unsigned short*)(ws + (4ll  << 20));    //  4..20
    unsigned short* Wc16 = (unsigned short*)(ws + (20ll << 20));    // 20..28
    unsigned short* Wr16 = (unsigned short*)(ws + (28ll << 20));    // 28..36
    unsigned* cnt  = (unsigned*)(ws + (36ll << 20));                // 4 B
    unsigned* list = (unsigned*)(ws + (36ll << 20) + 16);           // 1 MiB

    convert_kernel<<<dim3(20480), dim3(256), 0, stream>>>(
        x, state, win, wgate, wres, X16, S16, Wc16, Wr16, out, cnt);

    fused_step<<<dim3(256), dim3(512), 0, stream>>>(
        X16, S16, Wc16, Wr16, state, out, cnt, list);

    fixup_kernel<<<dim3(1024), dim3(256), 0, stream>>>(
        x, state, win, wres, wgate, cnt, list, out);
}

// Round 10
// 377.298 us; speedup vs baseline: 1.0678x; 1.0678x over previous
//
#include <hip/hip_runtime.h>
#include <math.h>

// GatedSpikingReservoirStep — fp16-single MFMA fused kernel + fp64 fixup.
// Round 16: CONCURRENCY x BYTES. r9 falsified the constant-rate staging
// model (bytes halved, time identical, rate dropped to 3 TB/s). The model
// fitting ALL of r0-r9: wall = staged_bytes_per_CU / rate(waves,streams):
// 8w/1blk->5 B/cy (r9), 8w/2blk->8.5 (r1), 16w/4blk->10.3 (r6). No round
// yet combined high waves/CU with low bytes. This round: 128x128 tile,
// 512 threads = 8 waves x (64x32 sub-tile; acc[4][2]+u[4][2]=64 regs, r6
// measured VGPR=64 at this shape), grid 512 = 2 blocks/CU -> 16 waves/CU
// at r1's 1.07 GB staged. Predicted 175-205us (vs 253). r1's proven
// schedule (sync/gld16/sync/read/mfma), r0's conflict-free chunk-XOR LDS
// swizzle, bijective XCD chunk mapping (512 blocks, 64/XCD).
// fixup: 16-lane groups (width-16 shuffles, 4 elem/wave) -> ~4x parallelism.
// Identical fp32 epilogue algebra -> absmax unchanged.

#define IDIM 512
#define DDIM 2048
#define MAXD 2560
#define BDIM 4096
#define LIST_CAP 262144
#define BAND 4e-3f

typedef __attribute__((ext_vector_type(4))) float f32x4;
typedef __attribute__((ext_vector_type(8))) _Float16 f16x8;

__device__ __forceinline__ void gld16(const unsigned short* g, unsigned short* l) {
    __builtin_amdgcn_global_load_lds((const __attribute__((address_space(1))) void*)g,
                                     (__attribute__((address_space(3))) void*)l,
                                     16, 0, 0);
}
__device__ __forceinline__ float sigf(float x) { return 1.0f / (1.0f + __expf(-x)); }

// ---------------------------------------------------------------------------
// convert: fp32 -> fp16 for X, S=state[:, :2048], Wc=[Win;Wgate], Wr;
// zero out-pad; zero fixup counter. 20480 blocks x 256 (float4 units).
// ---------------------------------------------------------------------------
__global__ __launch_bounds__(256) void convert_kernel(
    const float* __restrict__ x, const float* __restrict__ state,
    const float* __restrict__ win, const float* __restrict__ wgate,
    const float* __restrict__ wres,
    unsigned short* __restrict__ X16, unsigned short* __restrict__ S16,
    unsigned short* __restrict__ Wc16, unsigned short* __restrict__ Wr16,
    float* __restrict__ out, unsigned* __restrict__ cnt)
{
    int idx = blockIdx.x * 256 + threadIdx.x;
    if (idx == 0) *cnt = 0u;
    float4 v;
    unsigned short* p;
    long off;
    if (idx < 524288) {
        v = ((const float4*)x)[idx];
        p = X16; off = (long)idx * 4;
    } else if (idx < 2621440) {
        int i = idx - 524288;
        int row = i >> 9, c4 = i & 511;
        v = *(const float4*)(state + (long)row * MAXD + c4 * 4);
        p = S16; off = (long)i * 4;
    } else if (idx < 3670016) {
        int i = idx - 2621440;
        v = (i < 262144) ? ((const float4*)win)[i] : ((const float4*)wgate)[i - 262144];
        p = Wc16; off = (long)i * 4;
    } else if (idx < 4718592) {
        int i = idx - 3670016;
        v = ((const float4*)wres)[i];
        p = Wr16; off = (long)i * 4;
    } else {
        int i = idx - 4718592;
        int row = i >> 7, c4 = i & 127;
        *(float4*)(out + (long)row * MAXD + DDIM + c4 * 4) = make_float4(0.f, 0.f, 0.f, 0.f);
        return;
    }
    _Float16 h0 = (_Float16)v.x, h1 = (_Float16)v.y;
    _Float16 h2 = (_Float16)v.z, h3 = (_Float16)v.w;
    ushort4 hv;
    hv.x = *(unsigned short*)&h0; hv.y = *(unsigned short*)&h1;
    hv.z = *(unsigned short*)&h2; hv.w = *(unsigned short*)&h3;
    *(ushort4*)(p + off) = hv;
}

// ---------------------------------------------------------------------------
// fused_step: 5 GEMM phases (virtual K=4096) + gating epilogue, 128x128 tile.
// 512 thr / 8 waves arranged 2m x 4n; wave owns 64x32 (acc[4][2]+u[4][2]).
// BK=32, single 16KB LDS buffer (A[128][32] + B[128][32] hw). Per K-step:
// sync; each wave stages 16 A-rows + 16 B-rows (2 gld16); sync; plain LDS
// fragment reads; 8 MFMA. r1-proven structure, r0-verified chunk-XOR swizzle.
// XCD mapping: 512 blocks, 64 consecutive nb per XCD = 8m x 8n tile chunk.
// ---------------------------------------------------------------------------
__global__ __launch_bounds__(512, 4) void fused_step(
    const unsigned short* __restrict__ X16, const unsigned short* __restrict__ S16,
    const unsigned short* __restrict__ Wc16, const unsigned short* __restrict__ Wr16,
    const float* __restrict__ state, float* __restrict__ out,
    unsigned* __restrict__ cnt, unsigned* __restrict__ list)
{
    __shared__ alignas(16) unsigned short lA[128 * 32];
    __shared__ alignas(16) unsigned short lB[128 * 32];
    const int t = threadIdx.x;
    const int wave = t >> 6, lane = t & 63;
    const int wm = wave >> 2, wn = wave & 3;             // 2m x 4n wave grid
    const int quad = lane >> 4, l16 = lane & 15;

    // bijective XCD swizzle: 512 blocks, tile grid 32m x 16n, 64 tiles/XCD
    const int bid = blockIdx.x;
    const int nb  = (bid & 7) * 64 + (bid >> 3);
    const int xcd = nb >> 6, lid = nb & 63;
    const int m0 = (((xcd >> 1) << 3) + (lid >> 3)) * 128;   // 32 m-tiles
    const int n0 = (((xcd & 1) << 3) + (lid & 7)) * 128;     // 16 n-tiles

    const int rowoff = lane >> 2;                         // 0..15
    const int kg = ((lane & 3) ^ ((lane >> 3) & 3)) * 8;  // write-side chunk swizzle (hw)
    const int krh = (quad ^ ((l16 >> 1) & 3)) * 8;        // read-side chunk (hw)

    f32x4 acc[4][2];
    f32x4 u[4][2];    // sum -> 0.2*tanh(i*sum) -> + 0.8*f*prev  (2 live sets)

    #pragma unroll
    for (int mi = 0; mi < 4; mi++)
        #pragma unroll
        for (int ni = 0; ni < 2; ni++)
            acc[mi][ni] = (f32x4)0.0f;

    auto phase = [&](const unsigned short* Ag, long ldA,
                     const unsigned short* Bg, long ldB, int klen) {
        const unsigned short* a0 = Ag + (long)(wave * 16 + rowoff) * ldA + kg;
        const unsigned short* b0 = Bg + (long)(wave * 16 + rowoff) * ldB + kg;
        unsigned short* dA = lA + wave * 512;             // 16 rows x 32 hw
        unsigned short* dB = lB + wave * 512;
        for (int k0 = 0; k0 < klen; k0 += 32) {
            __syncthreads();
            gld16(a0 + k0, dA);
            gld16(b0 + k0, dB);
            __syncthreads();
            f16x8 af[4], bf[2];
            #pragma unroll
            for (int mi = 0; mi < 4; mi++)
                af[mi] = *(const f16x8*)&lA[(wm * 64 + mi * 16 + l16) * 32 + krh];
            #pragma unroll
            for (int ni = 0; ni < 2; ni++)
                bf[ni] = *(const f16x8*)&lB[(wn * 32 + ni * 16 + l16) * 32 + krh];
            #pragma unroll
            for (int mi = 0; mi < 4; mi++)
                #pragma unroll
                for (int ni = 0; ni < 2; ni++)
                    acc[mi][ni] = __builtin_amdgcn_mfma_f32_16x16x32_f16(af[mi], bf[ni], acc[mi][ni], 0, 0, 0);
        }
    };

    // Phase 0: acc = prev @ Wres^T          (K = 2048)
    phase(S16 + (long)m0 * DDIM, DDIM, Wr16 + (long)n0 * DDIM, DDIM, DDIM);
    // Phase 1: acc += X @ Win^T  -> u = ip + rp   (K = 512)
    phase(X16 + (long)m0 * IDIM, IDIM, Wc16 + (long)n0 * IDIM, IDIM, IDIM);
    #pragma unroll
    for (int mi = 0; mi < 4; mi++)
        #pragma unroll
        for (int ni = 0; ni < 2; ni++) { u[mi][ni] = acc[mi][ni]; acc[mi][ni] = (f32x4)0.0f; }

    // Phase 2: acc = X @ Wg_i^T  -> u = 0.2*tanh(sig(acc)*u)
    phase(X16 + (long)m0 * IDIM, IDIM, Wc16 + (long)(DDIM + n0) * IDIM, IDIM, IDIM);
    #pragma unroll
    for (int mi = 0; mi < 4; mi++)
        #pragma unroll
        for (int ni = 0; ni < 2; ni++) {
            #pragma unroll
            for (int r = 0; r < 4; r++)
                u[mi][ni][r] = 0.2f * tanhf(sigf(acc[mi][ni][r]) * u[mi][ni][r]);
            acc[mi][ni] = (f32x4)0.0f;
        }

    // Phase 3: acc = X @ Wg_f^T  -> u += 0.8*sig(acc)*prev
    phase(X16 + (long)m0 * IDIM, IDIM, Wc16 + (long)(2 * DDIM + n0) * IDIM, IDIM, IDIM);
    #pragma unroll
    for (int mi = 0; mi < 4; mi++)
        #pragma unroll
        for (int ni = 0; ni < 2; ni++) {
            #pragma unroll
            for (int r = 0; r < 4; r++) {
                int row = m0 + wm * 64 + mi * 16 + quad * 4 + r;
                int col = n0 + wn * 32 + ni * 16 + l16;
                float prev = state[(long)row * MAXD + col];
                u[mi][ni][r] += 0.8f * sigf(acc[mi][ni][r]) * prev;
            }
            acc[mi][ni] = (f32x4)0.0f;
        }

    // Phase 4: acc = X @ Wg_o^T  -> ns = sig(acc)*u -> spike -> write
    phase(X16 + (long)m0 * IDIM, IDIM, Wc16 + (long)(3 * DDIM + n0) * IDIM, IDIM, IDIM);
    #pragma unroll
    for (int mi = 0; mi < 4; mi++)
        #pragma unroll
        for (int ni = 0; ni < 2; ni++) {
            #pragma unroll
            for (int r = 0; r < 4; r++) {
                int row = m0 + wm * 64 + mi * 16 + quad * 4 + r;
                int col = n0 + wn * 32 + ni * 16 + l16;
                float go = sigf(acc[mi][ni][r]);
                float ns = go * u[mi][ni][r];
                float ov = (ns > 0.5f) ? ns - 0.5f : ns;
                out[(long)row * MAXD + col] = ov;
                if (fabsf(ns - 0.5f) < BAND) {
                    unsigned pos = atomicAdd(cnt, 1u);
                    if (pos < LIST_CAP) list[pos] = (unsigned)(row * DDIM + col);
                }
            }
        }
}

// ---------------------------------------------------------------------------
// fixup: recompute flagged elements exactly in fp64. 16-lane groups
// (4 elements per wave), float4-vectorized loads, width-16 shuffles.
// ---------------------------------------------------------------------------
__global__ __launch_bounds__(256) void fixup_kernel(
    const float* __restrict__ x, const float* __restrict__ state,
    const float* __restrict__ win, const float* __restrict__ wres,
    const float* __restrict__ wgate,
    const unsigned* __restrict__ cnt, const unsigned* __restrict__ list,
    float* __restrict__ out)
{
    const int grp  = (blockIdx.x * 256 + threadIdx.x) >> 4;   // global 16-lane group
    const int l16  = threadIdx.x & 15;
    const int ngrp = gridDim.x * 16;
    unsigned n = *cnt;
    if (n > LIST_CAP) n = LIST_CAP;
    for (unsigned e = grp; e < n; e += ngrp) {
        unsigned rc = list[e];
        int row = rc >> 11, col = rc & 2047;
        double ip = 0.0, gi = 0.0, gf = 0.0, go = 0.0, rp = 0.0;
        const float* xr  = x + (long)row * IDIM;
        const float* wi  = win + (long)col * IDIM;
        const float* wgi = wgate + (long)col * IDIM;
        const float* wgf = wgate + (long)(DDIM + col) * IDIM;
        const float* wgo = wgate + (long)(2 * DDIM + col) * IDIM;
        #pragma unroll 2
        for (int k = l16 * 4; k < IDIM; k += 64) {
            float4 xv = *(const float4*)(xr + k);
            float4 a = *(const float4*)(wi + k);
            float4 b = *(const float4*)(wgi + k);
            float4 c = *(const float4*)(wgf + k);
            float4 d = *(const float4*)(wgo + k);
            ip += (double)xv.x * a.x + (double)xv.y * a.y + (double)xv.z * a.z + (double)xv.w * a.w;
            gi += (double)xv.x * b.x + (double)xv.y * b.y + (double)xv.z * b.z + (double)xv.w * b.w;
            gf += (double)xv.x * c.x + (double)xv.y * c.y + (double)xv.z * c.z + (double)xv.w * c.w;
            go += (double)xv.x * d.x + (double)xv.y * d.y + (double)xv.z * d.z + (double)xv.w * d.w;
        }
        const float* sr = state + (long)row * MAXD;
        const float* wr_ = wres + (long)col * DDIM;
        #pragma unroll 4
        for (int k = l16 * 4; k < DDIM; k += 64) {
            float4 sv = *(const float4*)(sr + k);
            float4 wv = *(const float4*)(wr_ + k);
            rp += (double)sv.x * wv.x + (double)sv.y * wv.y + (double)sv.z * wv.z + (double)sv.w * wv.w;
        }
        #pragma unroll
        for (int o = 8; o > 0; o >>= 1) {
            ip += __shfl_down(ip, o, 16);
            gi += __shfl_down(gi, o, 16);
            gf += __shfl_down(gf, o, 16);
            go += __shfl_down(go, o, 16);
            rp += __shfl_down(rp, o, 16);
        }
        if (l16 == 0) {
            double si = 1.0 / (1.0 + exp(-gi));
            double sf = 1.0 / (1.0 + exp(-gf));
            double so = 1.0 / (1.0 + exp(-go));
            double prev = (double)state[(long)row * MAXD + col];
            double ns = so * (0.8 * sf * prev + 0.2 * tanh(si * (ip + rp)));
            if (ns > 0.5) ns -= 0.5;
            out[(long)row * MAXD + col] = (float)ns;
        }
    }
}

extern "C" void kernel_launch(void* const* d_in, const int* in_sizes, int n_in,
                              void* d_out, int out_size, void* d_ws, size_t ws_size,
                              hipStream_t stream) {
    const float* x     = (const float*)d_in[0];   // (4096, 512)
    const float* state = (const float*)d_in[1];   // (4096, 2560)
    const float* win   = (const float*)d_in[2];   // (2048, 512)
    const float* wres  = (const float*)d_in[3];   // (2048, 2048)
    const float* wgate = (const float*)d_in[4];   // (6144, 512)
    float* out = (float*)d_out;

    char* ws = (char*)d_ws;
    unsigned short* X16  = (unsigned short*)(ws);                   //  0.. 4 MiB
    unsigned short* S16  = (unsigned short*)(ws + (4ll  << 20));    //  4..20
    unsigned short* Wc16 = (unsigned short*)(ws + (20ll << 20));    // 20..28
    unsigned short* Wr16 = (unsigned short*)(ws + (28ll << 20));    // 28..36
    unsigned* cnt  = (unsigned*)(ws + (36ll << 20));                // 4 B
    unsigned* list = (unsigned*)(ws + (36ll << 20) + 16);           // 1 MiB

    convert_kernel<<<dim3(20480), dim3(256), 0, stream>>>(
        x, state, win, wgate, wres, X16, S16, Wc16, Wr16, out, cnt);

    fused_step<<<dim3(512), dim3(512), 0, stream>>>(
        X16, S16, Wc16, Wr16, state, out, cnt, list);

    fixup_kernel<<<dim3(1024), dim3(256), 0, stream>>>(
        x, state, win, wres, wgate, cnt, list, out);
}